// Round 1
// baseline (1183.264 us; speedup 1.0000x reference)
//
#include <hip/hip_runtime.h>

#define BB 64
#define LL 512
#define DD 1024
#define CC 131
#define CP 132
#define START_I 129
#define STOP_I 130
#define NEGV -10000.0f

// ---------------- Kernel 1: feats[m][c] = dot(x[m,:], W[c,:]) + b[c] ----------------
// grid 512 blocks (64 rows each), 256 threads. KC=32 k-chunks staged in LDS.
__global__ __launch_bounds__(256) void gemm_feats(
    const float* __restrict__ x, const float* __restrict__ W,
    const float* __restrict__ bias, float* __restrict__ feats)
{
    // xs: 64 rows x 32 k (stride 36); ws: 132 rows x 32 k (stride 36); epilogue reuses as 8448 floats
    __shared__ float lds[8448];
    float* xs = lds;              // [64][36]
    float* ws = lds + 64 * 36;    // [132][36]

    const int tid = threadIdx.x;
    const int m0 = blockIdx.x * 64;
    const int m  = tid & 63;
    const int cg = tid >> 6;      // 0..3, wave-uniform

    float acc[33];
#pragma unroll
    for (int j = 0; j < 33; ++j) acc[j] = 0.f;

    for (int kc = 0; kc < 32; ++kc) {
        const int k0 = kc * 32;
        if (kc) __syncthreads();
        // stage x: 64 rows x 32 cols = 512 float4
#pragma unroll
        for (int q = 0; q < 2; ++q) {
            int lin = tid + q * 256;           // 0..511
            int r = lin >> 3, c4 = lin & 7;
            float4 v = *(const float4*)&x[(size_t)(m0 + r) * DD + k0 + c4 * 4];
            *(float4*)&xs[r * 36 + c4 * 4] = v;
        }
        // stage W: 131 rows x 32 cols = 1048 float4
#pragma unroll
        for (int q = 0; q < 5; ++q) {
            int lin = tid + q * 256;
            if (lin < CC * 8) {
                int r = lin >> 3, c4 = lin & 7;
                float4 v = *(const float4*)&W[(size_t)r * DD + k0 + c4 * 4];
                *(float4*)&ws[r * 36 + c4 * 4] = v;
            }
        }
        if (tid < 8) *(float4*)&ws[CC * 36 + tid * 4] = make_float4(0.f, 0.f, 0.f, 0.f); // pad row
        __syncthreads();

        float4 xr[8];
#pragma unroll
        for (int k4 = 0; k4 < 8; ++k4) xr[k4] = *(const float4*)&xs[m * 36 + k4 * 4];
#pragma unroll
        for (int j = 0; j < 33; ++j) {
            const float* wr = &ws[(cg * 33 + j) * 36];   // wave-uniform row -> broadcast reads
            float s = acc[j];
#pragma unroll
            for (int k4 = 0; k4 < 8; ++k4) {
                float4 wv = *(const float4*)&wr[k4 * 4];
                s = fmaf(xr[k4].x, wv.x, s);
                s = fmaf(xr[k4].y, wv.y, s);
                s = fmaf(xr[k4].z, wv.z, s);
                s = fmaf(xr[k4].w, wv.w, s);
            }
            acc[j] = s;
        }
    }

    // epilogue: add bias, round-trip through LDS for coalesced float4 stores
    __syncthreads();
#pragma unroll
    for (int j = 0; j < 33; ++j) {
        int c = cg * 33 + j;
        float bv = (c < CC) ? bias[c] : 0.f;
        lds[m * CP + c] = acc[j] + bv;
    }
    __syncthreads();
#pragma unroll
    for (int q = 0; q < 9; ++q) {
        int lin = tid + q * 256;              // float4 index, total 64*132/4 = 2112
        if (lin < (64 * CP) / 4) {
            float4 v = *(const float4*)&lds[lin * 4];
            *(float4*)&feats[(size_t)m0 * CP + lin * 4] = v;
        }
    }
}

// ---------------- Kernel 2: Viterbi forward, value-only; stores score history ----------------
// grid 64 (one batch per block), 192 threads (lane j = current tag, j<131 active).
__global__ __launch_bounds__(192, 1) void viterbi_fwd(
    const float* __restrict__ feats, const float* __restrict__ mask,
    const float* __restrict__ trans, float* __restrict__ hist)
{
    const int b = blockIdx.x;
    const int j = threadIdx.x;
    const int jr = (j < CC) ? j : (CC - 1);   // clamp inactive lanes to a valid row
    __shared__ float sbuf[2][CP];

    float Trow[CP];
#pragma unroll
    for (int i = 0; i < CC; ++i) Trow[i] = trans[(size_t)jr * CC + i];
    Trow[CC] = NEGV;

    if (j < CP) {
        sbuf[0][j] = (j == START_I) ? 0.f : NEGV;
        sbuf[1][j] = NEGV;                    // pad slot 131 stays NEGV forever
    }
    float s_reg = (j == START_I) ? 0.f : NEGV;
    __syncthreads();

    const float* fb = feats + (size_t)b * LL * CP;
    const float* mb = mask + (size_t)b * LL;
    float* hb = hist + (size_t)b * LL * CP;

    const int jc = (j < CP) ? j : (CP - 1);
    float fv = fb[jc];
    float mv = mb[0];

    int cur = 0;
    float ns_prev = 0.f;
    for (int t = 0; t < LL; ++t) {
        // deferred history store from previous step (lands after the barrier -> drains during compute)
        if (t > 0 && j < CC) hb[(size_t)(t - 1) * CP + j] = ns_prev;
        // prefetch next feat/mask (consumed at end of this step -> hides latency)
        float fv_n = 0.f, mv_n = 1.f;
        if (t + 1 < LL) { fv_n = fb[(size_t)(t + 1) * CP + jc]; mv_n = mb[t + 1]; }

        const float4* s4 = (const float4*)sbuf[cur];
        float mx0 = -3.0e38f, mx1 = -3.0e38f;
#pragma unroll
        for (int i4 = 0; i4 < 33; ++i4) {
            float4 sv = s4[i4];
            mx0 = fmaxf(fmaxf(mx0, sv.x + Trow[i4 * 4 + 0]), sv.y + Trow[i4 * 4 + 1]);
            mx1 = fmaxf(fmaxf(mx1, sv.z + Trow[i4 * 4 + 2]), sv.w + Trow[i4 * 4 + 3]);
        }
        float best = fmaxf(mx0, mx1);
        float ns = (mv != 0.f) ? (best + fv) : s_reg;   // mask is binary -> select == blend
        s_reg = ns;
        if (j < CC) sbuf[cur ^ 1][j] = ns;
        __syncthreads();
        ns_prev = ns;
        fv = fv_n; mv = mv_n;
        cur ^= 1;
    }
    if (j < CC) hb[(size_t)(LL - 1) * CP + j] = ns_prev;
}

// ---------------- Kernel 3: backtrack by exact recompute of argmax ----------------
// grid 64 (one batch per block), 64 threads (one wave). Slots i = lane, lane+64, lane+128.
__global__ __launch_bounds__(64, 1) void viterbi_btr(
    const float* __restrict__ hist, const float* __restrict__ trans,
    float* __restrict__ out_score, float* __restrict__ out_path)
{
    const int b = blockIdx.x;
    const int lane = threadIdx.x;
    const float* hb = hist + (size_t)b * LL * CP;
    const int i0 = lane, i1 = lane + 64, i2 = lane + 128;
    const bool a2 = (i2 < CC);   // lanes 0..2 only

    // final argmax: hist[L-1] + trans[STOP]
    float v0 = hb[(size_t)(LL - 1) * CP + i0] + trans[(size_t)STOP_I * CC + i0];
    float v1 = hb[(size_t)(LL - 1) * CP + i1] + trans[(size_t)STOP_I * CC + i1];
    float v2 = a2 ? (hb[(size_t)(LL - 1) * CP + i2] + trans[(size_t)STOP_I * CC + i2]) : -3.0e38f;

    float best = v0; int idx = i0;
    if (v1 > best) { best = v1; idx = i1; }
    if (v2 > best) { best = v2; idx = i2; }
#pragma unroll
    for (int off = 32; off >= 1; off >>= 1) {
        float ob = __shfl_xor(best, off, 64);
        int   oi = __shfl_xor(idx, off, 64);
        if (ob > best || (ob == best && oi < idx)) { best = ob; idx = oi; }
    }
    if (lane == 0) {
        out_score[b] = best;
        out_path[(size_t)b * LL + (LL - 1)] = (float)idx;
    }
    int tag = idx;

    // prefetch hist[L-2]
    float h0 = hb[(size_t)(LL - 2) * CP + i0];
    float h1 = hb[(size_t)(LL - 2) * CP + i1];
    float h2 = a2 ? hb[(size_t)(LL - 2) * CP + i2] : 0.f;

    for (int t = LL - 1; t >= 1; --t) {
        float hn0 = 0.f, hn1 = 0.f, hn2 = 0.f;
        if (t >= 2) {
            hn0 = hb[(size_t)(t - 2) * CP + i0];
            hn1 = hb[(size_t)(t - 2) * CP + i1];
            hn2 = a2 ? hb[(size_t)(t - 2) * CP + i2] : 0.f;
        }
        const float* tr = trans + (size_t)tag * CC;   // dependent load (tag from prev step)
        float w0 = h0 + tr[i0];
        float w1 = h1 + tr[i1];
        float w2 = a2 ? (h2 + tr[i2]) : -3.0e38f;

        float bb = w0; int ii = i0;
        if (w1 > bb) { bb = w1; ii = i1; }
        if (w2 > bb) { bb = w2; ii = i2; }
#pragma unroll
        for (int off = 32; off >= 1; off >>= 1) {
            float ob = __shfl_xor(bb, off, 64);
            int   oi = __shfl_xor(ii, off, 64);
            if (ob > bb || (ob == bb && oi < ii)) { bb = ob; ii = oi; }
        }
        tag = ii;
        if (lane == 0) out_path[(size_t)b * LL + (t - 1)] = (float)tag;
        h0 = hn0; h1 = hn1; h2 = hn2;
    }
}

extern "C" void kernel_launch(void* const* d_in, const int* in_sizes, int n_in,
                              void* d_out, int out_size, void* d_ws, size_t ws_size,
                              hipStream_t stream)
{
    const float* x     = (const float*)d_in[0];
    const float* mask  = (const float*)d_in[1];
    const float* W     = (const float*)d_in[2];
    const float* bias  = (const float*)d_in[3];
    const float* trans = (const float*)d_in[4];

    float* feats = (float*)d_ws;                               // 32768*132 floats
    float* hist  = feats + (size_t)BB * LL * CP;               // 64*512*132 floats
    float* out_score = (float*)d_out;
    float* out_path  = out_score + BB;

    hipLaunchKernelGGL(gemm_feats, dim3((BB * LL) / 64), dim3(256), 0, stream, x, W, bias, feats);
    hipLaunchKernelGGL(viterbi_fwd, dim3(BB), dim3(192), 0, stream, feats, mask, trans, hist);
    hipLaunchKernelGGL(viterbi_btr, dim3(BB), dim3(64), 0, stream, hist, trans, out_score, out_path);
}